// Round 1
// baseline (133.586 us; speedup 1.0000x reference)
//
#include <hip/hip_runtime.h>

// Temporal IF-neuron spike quantizer.
// x: [T*B, TOK, DIM] fp32, viewed as [T][S] with S = B*TOK*DIM spatial elems.
// Per spatial elem: mem=lam/2; for t: mem+=x; k=clamp((int)(mem*128/lam),0,255);
//                   out=lam*k; mem-=lam*k.
// (sum over bit planes of lam*2^j*bit_j == lam*k — bit-plane decomposition is
//  an identity, so no per-plane work is needed.)

#define T_STEPS 4

__global__ __launch_bounds__(256) void spike_scan_kernel(
    const float4* __restrict__ x,
    const float* __restrict__ lam_p,
    float4* __restrict__ out,
    int n4,        // float4 count per timestep plane (S/4)
    int total4)    // guard
{
    int i = blockIdx.x * blockDim.x + threadIdx.x;
    if (i >= n4) return;

    const float lam = lam_p[0];
    const float half_lam = 0.5f * lam;

    float4 mem = make_float4(half_lam, half_lam, half_lam, half_lam);

#pragma unroll
    for (int t = 0; t < T_STEPS; ++t) {
        float4 xv = x[(size_t)t * n4 + i];
        float4 sp;

        // component-wise scan step
        {
            float m = mem.x + xv.x;
            int k = (int)((m * 128.0f) / lam);      // trunc toward zero, matches astype(int32)
            k = k < 0 ? 0 : (k > 255 ? 255 : k);
            float s = lam * (float)k;
            sp.x = s; mem.x = m - s;
        }
        {
            float m = mem.y + xv.y;
            int k = (int)((m * 128.0f) / lam);
            k = k < 0 ? 0 : (k > 255 ? 255 : k);
            float s = lam * (float)k;
            sp.y = s; mem.y = m - s;
        }
        {
            float m = mem.z + xv.z;
            int k = (int)((m * 128.0f) / lam);
            k = k < 0 ? 0 : (k > 255 ? 255 : k);
            float s = lam * (float)k;
            sp.z = s; mem.z = m - s;
        }
        {
            float m = mem.w + xv.w;
            int k = (int)((m * 128.0f) / lam);
            k = k < 0 ? 0 : (k > 255 ? 255 : k);
            float s = lam * (float)k;
            sp.w = s; mem.w = m - s;
        }

        out[(size_t)t * n4 + i] = sp;
    }
    (void)total4;
}

extern "C" void kernel_launch(void* const* d_in, const int* in_sizes, int n_in,
                              void* d_out, int out_size, void* d_ws, size_t ws_size,
                              hipStream_t stream) {
    const float* x = (const float*)d_in[0];
    const float* lam = (const float*)d_in[1];
    float* out = (float*)d_out;

    const int total = in_sizes[0];          // T*B*TOK*DIM
    const int spatial = total / T_STEPS;    // B*TOK*DIM
    const int n4 = spatial / 4;             // divisible: 4,816,896 / 4

    const int block = 256;
    const int grid = (n4 + block - 1) / block;

    spike_scan_kernel<<<grid, block, 0, stream>>>(
        (const float4*)x, lam, (float4*)out, n4, total / 4);
}

// Round 3
// 132.835 us; speedup vs baseline: 1.0057x; 1.0057x over previous
//
#include <hip/hip_runtime.h>

// Temporal IF-neuron spike quantizer, collapsed form:
//   mem = lam/2
//   for t: mem += x[t]; k = clamp(trunc(mem*128/lam), 0, 255);
//          out[t] = lam*k; mem -= lam*k
// (sum_j lam*2^j*bit_j(k) == lam*k — the bit-plane decomposition is an identity)
//
// Memory-bound: 77 MB in + 77 MB out. Strategy: native float-vector lanes
// (ext_vector_type so nontemporal builtins accept them), all 4 temporal plane
// loads issued up-front (ILP), nontemporal load/store (streaming, zero reuse),
// divide replaced by one precomputed reciprocal multiply.

#define T_STEPS 4

typedef float vf4 __attribute__((ext_vector_type(4)));

__device__ __forceinline__ vf4 step4(vf4& mem, const vf4 xv,
                                     const float lam, const float inv) {
    vf4 sp;
#pragma unroll
    for (int c = 0; c < 4; ++c) {
        float m = mem[c] + xv[c];
        int k = (int)(m * inv);                 // trunc toward zero == astype(int32)
        k = k < 0 ? 0 : (k > 255 ? 255 : k);
        float s = lam * (float)k;
        sp[c] = s;
        mem[c] = m - s;
    }
    return sp;
}

__global__ __launch_bounds__(256) void spike_scan_kernel(
    const vf4* __restrict__ x,
    const float* __restrict__ lam_p,
    vf4* __restrict__ out,
    int n4)        // vf4 count per timestep plane (S/4)
{
    int i = blockIdx.x * blockDim.x + threadIdx.x;
    if (i >= n4) return;

    const float lam = lam_p[0];
    const float inv = 128.0f / lam;             // one divide, hoisted
    const float half_lam = 0.5f * lam;

    // Issue all 4 plane loads before any compute: 4 outstanding dwordx4.
    const vf4* p0 = x + i;
    vf4 xv0 = __builtin_nontemporal_load(p0);
    vf4 xv1 = __builtin_nontemporal_load(p0 + (size_t)n4);
    vf4 xv2 = __builtin_nontemporal_load(p0 + (size_t)2 * n4);
    vf4 xv3 = __builtin_nontemporal_load(p0 + (size_t)3 * n4);

    vf4 mem = {half_lam, half_lam, half_lam, half_lam};

    vf4 sp0 = step4(mem, xv0, lam, inv);
    __builtin_nontemporal_store(sp0, out + i);
    vf4 sp1 = step4(mem, xv1, lam, inv);
    __builtin_nontemporal_store(sp1, out + (size_t)n4 + i);
    vf4 sp2 = step4(mem, xv2, lam, inv);
    __builtin_nontemporal_store(sp2, out + (size_t)2 * n4 + i);
    vf4 sp3 = step4(mem, xv3, lam, inv);
    __builtin_nontemporal_store(sp3, out + (size_t)3 * n4 + i);
}

extern "C" void kernel_launch(void* const* d_in, const int* in_sizes, int n_in,
                              void* d_out, int out_size, void* d_ws, size_t ws_size,
                              hipStream_t stream) {
    const float* x = (const float*)d_in[0];
    const float* lam = (const float*)d_in[1];
    float* out = (float*)d_out;

    const int total = in_sizes[0];          // T*B*TOK*DIM
    const int spatial = total / T_STEPS;    // B*TOK*DIM
    const int n4 = spatial / 4;             // 4,816,896 / 4 = 1,204,224

    const int block = 256;
    const int grid = (n4 + block - 1) / block;

    spike_scan_kernel<<<grid, block, 0, stream>>>(
        (const vf4*)x, lam, (vf4*)out, n4);
}